// Round 9
// baseline (190.511 us; speedup 1.0000x reference)
//
#include <hip/hip_runtime.h>
#include <hip/hip_bf16.h>
#include <math.h>

// Problem constants: B=2, S=2048, D=1024, H=16, HD=64
typedef unsigned short ushort_t;
typedef unsigned char uchar_t;
typedef __attribute__((ext_vector_type(8))) short short8;   // 8 bf16 = 4 VGPRs (MFMA A/B frag)
typedef __attribute__((ext_vector_type(4))) float f32x4;    // MFMA C/D frag

struct __align__(8) us4 { ushort_t u[4]; };

__device__ __forceinline__ ushort_t f2bf(float x) {
  union { float f; unsigned u; } c; c.f = x;
  unsigned r = c.u + 0x7FFFu + ((c.u >> 16) & 1u);  // RNE
  return (ushort_t)(r >> 16);
}
__device__ __forceinline__ float bf2f(ushort_t b) {
  union { unsigned u; float f; } c; c.u = ((unsigned)b) << 16;
  return c.f;
}

// (1/sqrt(2048)) * log2(e): folded into Q at projection time so the QK^T
// MFMA emits log2-domain scores directly.
#define CEXP_SCALE (0.02209708691f * 1.44269504089f)

// ---------------------------------------------------------------------------
// fp32 -> bf16 bulk convert — all four arrays in one launch (verified r3).
// ---------------------------------------------------------------------------
struct CvtArgs { const float* s[4]; ushort_t* d[4]; };

__global__ __launch_bounds__(256) void cvt_all(CvtArgs c) {
  int bid = blockIdx.x;
  int job, base;
  if (bid < 4096) { job = 0; base = bid; }
  else { job = 1 + ((bid - 4096) >> 10); base = (bid - 4096) & 1023; }
  int i = (base * 256 + threadIdx.x) * 4;
  f32x4 v = *(const f32x4*)(c.s[job] + i);
  us4 o;
  o.u[0] = f2bf(v[0]); o.u[1] = f2bf(v[1]); o.u[2] = f2bf(v[2]); o.u[3] = f2bf(v[3]);
  *(us4*)(c.d[job] + i) = o;
}

// ---------------------------------------------------------------------------
// QKV projection GEMM — BK=64 (was 32): halves barrier count (16 k-iters),
// 32 MFMA per barrier pair. Same green sync pattern (stage -> sync ->
// compute -> sync), same global_load_lds discipline (uniform dest + lane*16B;
// chunk = 8 rows x 128B). LDS 32KB -> 3 blocks/CU unchanged. Epilogues
// verbatim: z==0 Q scaled by CEXP_SCALE, z==1 K hd-swizzled, z==2 fp8 V^T.
// ---------------------------------------------------------------------------
struct QkvArgs {
  const ushort_t* X;
  const ushort_t* W0; const ushort_t* W1; const ushort_t* W2;
  const float* b0; const float* b1; const float* b2;
  ushort_t* o0; ushort_t* o1;
  uchar_t* vt;
};

__global__ __launch_bounds__(256) void qkv_gemm(QkvArgs a) {
  __shared__ __align__(16) ushort_t As[128 * 64];
  __shared__ __align__(16) ushort_t Bs[128 * 64];
  const int z = blockIdx.z;
  const ushort_t* W  = (z == 0) ? a.W0 : ((z == 1) ? a.W1 : a.W2);
  const float* bias  = (z == 0) ? a.b0 : ((z == 1) ? a.b1 : a.b2);
  const int mBase = blockIdx.x * 128;
  const int nBase = blockIdx.y * 128;
  const int tid  = threadIdx.x;
  const int lane = tid & 63;
  const int w    = tid >> 6;
  const int wm   = w >> 1, wn = w & 1;
  const int quad = lane >> 4;
  const int l15  = lane & 15;

  f32x4 acc[4][4] = {};

  // Staging geometry: chunk j covers rows j*8..j*8+7, full 64-col width.
  // Per-lane source row = lane>>3, col = (lane&7)*8 (ushort) -> lane*16B in LDS.
  const int srow = lane >> 3;
  const int scol = (lane & 7) * 8;
  const ushort_t* gA0 = a.X + (mBase + srow) * 1024 + scol;
  const ushort_t* gB0 = W   + (nBase + srow) * 1024 + scol;

  for (int k0 = 0; k0 < 1024; k0 += 64) {
#pragma unroll
    for (int p = 0; p < 4; ++p) {
      int j = w * 4 + p;                      // 0..15
      __builtin_amdgcn_global_load_lds(
          (const __attribute__((address_space(1))) void*)(gA0 + j * 8 * 1024 + k0),
          (__attribute__((address_space(3))) void*)(As + j * 512), 16, 0, 0);
      __builtin_amdgcn_global_load_lds(
          (const __attribute__((address_space(1))) void*)(gB0 + j * 8 * 1024 + k0),
          (__attribute__((address_space(3))) void*)(Bs + j * 512), 16, 0, 0);
    }
    __syncthreads();
    short8 af[2][4], bfr[2][4];
#pragma unroll
    for (int kk = 0; kk < 2; ++kk) {
#pragma unroll
      for (int mi = 0; mi < 4; ++mi)
        af[kk][mi] = *(const short8*)(As + (wm * 64 + mi * 16 + l15) * 64 + kk * 32 + quad * 8);
#pragma unroll
      for (int ni = 0; ni < 4; ++ni)
        bfr[kk][ni] = *(const short8*)(Bs + (wn * 64 + ni * 16 + l15) * 64 + kk * 32 + quad * 8);
    }
#pragma unroll
    for (int kk = 0; kk < 2; ++kk)
#pragma unroll
      for (int mi = 0; mi < 4; ++mi)
#pragma unroll
        for (int ni = 0; ni < 4; ++ni)
          acc[mi][ni] = __builtin_amdgcn_mfma_f32_16x16x32_bf16(af[kk][mi], bfr[kk][ni], acc[mi][ni], 0, 0, 0);
    __syncthreads();
  }

  if (z == 2) {
    // ---- fused V epilogue: fp8 e4m3 V^T with key-unit XOR swizzle ----
#pragma unroll
    for (int ni = 0; ni < 4; ++ni) {
      int n = nBase + wn * 64 + ni * 16 + l15;
      float bv = bias[n];
      int h = n >> 6, hd = n & 63;
#pragma unroll
      for (int mi = 0; mi < 4; ++mi) {
        int m0 = mBase + wm * 64 + mi * 16 + quad * 4;
        int bb = m0 >> 11, s = m0 & 2047;
        float x0 = acc[mi][ni][0] + bv, x1 = acc[mi][ni][1] + bv;
        float x2 = acc[mi][ni][2] + bv, x3 = acc[mi][ni][3] + bv;
        unsigned int pk = __builtin_amdgcn_cvt_pk_fp8_f32(x0, x1, 0, false);
        pk = __builtin_amdgcn_cvt_pk_fp8_f32(x2, x3, pk, true);
        int dest = (s & ~127) + ((((s >> 4) & 7) ^ (hd & 7)) * 16) + (s & 15);
        *(unsigned int*)(a.vt + (size_t)(bb * 16 + h) * 131072 + (size_t)hd * 2048 + dest) = pk;
      }
    }
  } else {
    ushort_t* out = (z == 0) ? a.o0 : a.o1;
    const int swz = (z == 1) ? 7 : 0;            // hd-unit swizzle mask (K only)
    const float osc = (z == 0) ? CEXP_SCALE : 1.0f;  // fold softmax scale into Q
#pragma unroll
    for (int ni = 0; ni < 4; ++ni) {
      int n = nBase + wn * 64 + ni * 16 + l15;
      float bv = bias[n];
      int h = n >> 6, hd = n & 63;
      int hdHi = hd >> 3, hdLo = hd & 7;
#pragma unroll
      for (int mi = 0; mi < 4; ++mi) {
        int m0 = mBase + wm * 64 + mi * 16 + quad * 4;
#pragma unroll
        for (int r = 0; r < 4; ++r) {
          int m = m0 + r;
          int bb = m >> 11, s = m & 2047;
          int hdw = (((hdHi ^ (s & swz)) << 3) | hdLo);
          out[((bb * 16 + h) * 2048 + s) * 64 + hdw] = f2bf((acc[mi][ni][r] + bv) * osc);
        }
      }
    }
  }
}

// ---------------------------------------------------------------------------
// Attention — EXACT r5 GREEN TEXT (51.6 us verified). Two-barrier KT=128
// schedule, 4 waves x 32 q-rows, r5 remap, needP/boundary block-uniform,
// CEXP folded upstream. FROZEN after 3 NaN strikes on geometry restructures.
// ---------------------------------------------------------------------------
__global__ __launch_bounds__(256) void attn_kernel(const ushort_t* __restrict__ qb,
                                                   const ushort_t* __restrict__ kb,
                                                   const uchar_t* __restrict__ vT,
                                                   ushort_t* __restrict__ zb) {
  __shared__ __align__(16) ushort_t Ks[128 * 64];   // [key][hd] swizzled bf16
  __shared__ __align__(16) uchar_t  Vt[64 * 128];   // [hd][key] swizzled fp8
  __shared__ __align__(16) uchar_t  Ps[128 * 128];  // [q][key] swizzled fp8 (wave-private rows)
  // ---- bijective block remap (512 = 8 xcd * 2 hi * 8 xb * 4 ylo) ----
  const int n_lin = blockIdx.x + 16 * blockIdx.y;
  const int xcd = n_lin & 7;
  const int j   = n_lin >> 3;           // 0..63
  const int hi  = (j >> 5) & 1;
  const int xb  = (j >> 2) & 7;
  const int xq  = hi ? (15 - xb) : xb;  // 0..15
  const int bh  = xcd * 4 + (j & 3);    // 0..31

  const int qblk = xq * 128;
  const int tid  = threadIdx.x;
  const int lane = tid & 63;
  const int w    = tid >> 6;
  const int quad = lane >> 4;
  const int l15  = lane & 15;
  const int l7   = l15 & 7;

  const ushort_t* qpage = qb + (size_t)bh * (2048 * 64);
  const ushort_t* kpage = kb + (size_t)bh * (2048 * 64);
  const uchar_t*  vpage = vT + (size_t)bh * (64 * 2048);

  // Q fragments (constant across key tiles; Q global layout is linear)
  short8 qf[2][2];
#pragma unroll
  for (int nb = 0; nb < 2; ++nb) {
    int qg = qblk + w * 32 + nb * 16 + l15;
#pragma unroll
    for (int kd = 0; kd < 2; ++kd)
      qf[nb][kd] = *(const short8*)(qpage + (size_t)qg * 64 + kd * 32 + quad * 8);
  }

  float psum[2] = {0.f, 0.f};
  f32x4 o[4][2] = {};  // O^T: [hd block][q block]

  for (int kt = 0; kt < 2048; kt += 128) {
    const bool needP    = (kt >= qblk);   // block-uniform: PV work in this tile
    const bool boundary = (kt == qblk);   // block-uniform: only tile needing mask
    __syncthreads();  // prior tile's LDS reads complete before DMA overwrite

    // ---- async stage K tile (16 KB, 4 chunks/wave) ----
#pragma unroll
    for (int p = 0; p < 4; ++p) {
      int jj = w * 4 + p;
      __builtin_amdgcn_global_load_lds(
          (const __attribute__((address_space(1))) void*)(kpage + (size_t)kt * 64 + jj * 512 + lane * 8),
          (__attribute__((address_space(3))) void*)(Ks + jj * 512), 16, 0, 0);
    }
    // ---- async stage V^T tile (8 KB fp8, 2 chunks/wave) ----
    if (needP) {
#pragma unroll
      for (int p = 0; p < 2; ++p) {
        int jj = w * 2 + p;
        __builtin_amdgcn_global_load_lds(
            (const __attribute__((address_space(1))) void*)(vpage + (size_t)(jj * 8 + (lane >> 3)) * 2048 + kt + (lane & 7) * 16),
            (__attribute__((address_space(3))) void*)(Vt + jj * 1024), 16, 0, 0);
      }
    }
    __syncthreads();  // drain vmcnt -> staged data visible

    // ---- S^T = K*Q^T per 16-key slice; exp + psum + fp8 P pack ----
#pragma unroll
    for (int mb = 0; mb < 8; ++mb) {
      const ushort_t* krow = Ks + (mb * 16 + l15) * 64;
      short8 kf0 = *(const short8*)(krow + ((0 + quad) ^ l7) * 8);
      short8 kf1 = *(const short8*)(krow + ((4 + quad) ^ l7) * 8);
      f32x4 s0 = {}, s1 = {};
      s0 = __builtin_amdgcn_mfma_f32_16x16x32_bf16(kf0, qf[0][0], s0, 0, 0, 0);
      s0 = __builtin_amdgcn_mfma_f32_16x16x32_bf16(kf1, qf[0][1], s0, 0, 0, 0);
      s1 = __builtin_amdgcn_mfma_f32_16x16x32_bf16(kf0, qf[1][0], s1, 0, 0, 0);
      s1 = __builtin_amdgcn_mfma_f32_16x16x32_bf16(kf1, qf[1][1], s1, 0, 0, 0);
      const int keyb = kt + mb * 16 + quad * 4;
#pragma unroll
      for (int nb = 0; nb < 2; ++nb) {
        f32x4 s = nb ? s1 : s0;
        float p0 = __builtin_amdgcn_exp2f(s[0]);
        float p1 = __builtin_amdgcn_exp2f(s[1]);
        float p2 = __builtin_amdgcn_exp2f(s[2]);
        float p3 = __builtin_amdgcn_exp2f(s[3]);
        psum[nb] += (p0 + p1) + (p2 + p3);  // denominator: ALL keys (mask is post-softmax)
        if (needP) {
          unsigned int pk;
          if (boundary) {
            int qg = qblk + w * 32 + nb * 16 + l15;
            float m0 = (keyb + 0 >= qg) ? p0 : 0.f;
            float m1 = (keyb + 1 >= qg) ? p1 : 0.f;
            float m2 = (keyb + 2 >= qg) ? p2 : 0.f;
            float m3 = (keyb + 3 >= qg) ? p3 : 0.f;
            pk = __builtin_amdgcn_cvt_pk_fp8_f32(m0, m1, 0, false);
            pk = __builtin_amdgcn_cvt_pk_fp8_f32(m2, m3, pk, true);
          } else {
            pk = __builtin_amdgcn_cvt_pk_fp8_f32(p0, p1, 0, false);
            pk = __builtin_amdgcn_cvt_pk_fp8_f32(p2, p3, pk, true);
          }
          *(unsigned int*)(Ps + (w * 32 + nb * 16 + l15) * 128 + ((mb ^ l7) * 16) + quad * 4) = pk;
        }
      }
    }

    // ---- O^T += V^T * P^T in fp8 (skip fully-masked tiles) ----
    if (needP) {
#pragma unroll
      for (int kd = 0; kd < 4; ++kd) {
        const int un = ((kd * 2 + (quad >> 1)) ^ l7) * 16 + (quad & 1) * 8;
        long long pf0 = *(const long long*)(Ps + (w * 32 + l15) * 128 + un);
        long long pf1 = *(const long long*)(Ps + (w * 32 + 16 + l15) * 128 + un);
#pragma unroll
        for (int mb = 0; mb < 4; ++mb) {
          long long vf = *(const long long*)(Vt + (mb * 16 + l15) * 128 + un);
          o[mb][0] = __builtin_amdgcn_mfma_f32_16x16x32_fp8_fp8(vf, pf0, o[mb][0], 0, 0, 0);
          o[mb][1] = __builtin_amdgcn_mfma_f32_16x16x32_fp8_fp8(vf, pf1, o[mb][1], 0, 0, 0);
        }
      }
    }
  }

  // ---- final denominator reduce (across quads) + store ----
#pragma unroll
  for (int nb = 0; nb < 2; ++nb) {
    psum[nb] += __shfl_xor(psum[nb], 16, 64);
    psum[nb] += __shfl_xor(psum[nb], 32, 64);
    float rl = 1.0f / psum[nb];
    int qg = qblk + w * 32 + nb * 16 + l15;
#pragma unroll
    for (int mb = 0; mb < 4; ++mb)
#pragma unroll
      for (int r = 0; r < 4; ++r) {
        int hd = mb * 16 + quad * 4 + r;
        zb[((size_t)bh * 2048 + qg) * 64 + hd] = f2bf(o[mb][nb][r] * rl);
      }
  }
}

// ---------------------------------------------------------------------------
// Residual + LayerNorm with the reference's scrambled .view(b,s,-1) remap
// ---------------------------------------------------------------------------
__global__ __launch_bounds__(256) void ln_kernel(const float* __restrict__ emb,
                                                 const ushort_t* __restrict__ zb,
                                                 const float* __restrict__ gamma,
                                                 const float* __restrict__ beta,
                                                 float* __restrict__ out) {
  __shared__ float red[2][4];
  int row = blockIdx.x;
  int b = row >> 11, s = row & 2047;
  int h = s >> 7;
  int siHi = (s & 127) << 4;
  int tid = threadIdx.x;
  int dcol = tid * 4;
  int si = siHi | (dcol >> 6);
  int j = dcol & 63;

  f32x4 e4 = *(const f32x4*)(emb + (size_t)row * 1024 + dcol);
  us4 z4 = *(const us4*)(zb + (((size_t)(b * 16 + h) * 2048 + si) * 64 + j));
  float x0 = e4[0] + bf2f(z4.u[0]);
  float x1 = e4[1] + bf2f(z4.u[1]);
  float x2 = e4[2] + bf2f(z4.u[2]);
  float x3 = e4[3] + bf2f(z4.u[3]);

  float sum = x0 + x1 + x2 + x3;
  float sq  = x0 * x0 + x1 * x1 + x2 * x2 + x3 * x3;
#pragma unroll
  for (int off = 1; off <= 32; off <<= 1) {
    sum += __shfl_xor(sum, off, 64);
    sq  += __shfl_xor(sq,  off, 64);
  }
  int wv = tid >> 6;
  if ((tid & 63) == 0) { red[0][wv] = sum; red[1][wv] = sq; }
  __syncthreads();
  float ts = red[0][0] + red[0][1] + red[0][2] + red[0][3];
  float tq = red[1][0] + red[1][1] + red[1][2] + red[1][3];
  float mu = ts * (1.0f / 1024.0f);
  float var = tq * (1.0f / 1024.0f) - mu * mu;
  float rsig = rsqrtf(var + 1e-5f);

  f32x4 g4 = *(const f32x4*)(gamma + dcol);
  f32x4 b4 = *(const f32x4*)(beta + dcol);
  f32x4 o4;
  o4[0] = (x0 - mu) * rsig * g4[0] + b4[0];
  o4[1] = (x1 - mu) * rsig * g4[1] + b4[1];
  o4[2] = (x2 - mu) * rsig * g4[2] + b4[2];
  o4[3] = (x3 - mu) * rsig * g4[3] + b4[3];
  *(f32x4*)(out + (size_t)row * 1024 + dcol) = o4;
}

// ---------------------------------------------------------------------------
extern "C" void kernel_launch(void* const* d_in, const int* in_sizes, int n_in,
                              void* d_out, int out_size, void* d_ws, size_t ws_size,
                              hipStream_t stream) {
  (void)in_sizes; (void)n_in; (void)out_size; (void)ws_size;
  const float* emb   = (const float*)d_in[0];
  const float* Wq    = (const float*)d_in[1];
  const float* bq    = (const float*)d_in[2];
  const float* Wk    = (const float*)d_in[3];
  const float* bk    = (const float*)d_in[4];
  const float* Wv    = (const float*)d_in[5];
  const float* bv    = (const float*)d_in[6];
  const float* gamma = (const float*)d_in[7];
  const float* beta  = (const float*)d_in[8];
  float* out = (float*)d_out;

  char* ws = (char*)d_ws;
  ushort_t* Xbf  = (ushort_t*)(ws);                    // 8,388,608 B
  ushort_t* Wqb  = (ushort_t*)(ws + 8388608);          // 2,097,152 B each
  ushort_t* Wkb  = (ushort_t*)(ws + 10485760);
  ushort_t* Wvb  = (ushort_t*)(ws + 12582912);
  ushort_t* qbuf = (ushort_t*)(ws + 14680064);         // 8,388,608 B (pre-scaled by CEXP)
  ushort_t* kbuf = (ushort_t*)(ws + 23068672);         // 8,388,608 B (hd-swizzled)
  ushort_t* zbuf = (ushort_t*)(ws + 31457280);         // attn output
  uchar_t*  vTb  = (uchar_t*)(ws + 39845888);          // 4,194,304 B fp8 V^T (key-swizzled)

  CvtArgs c;
  c.s[0] = emb; c.s[1] = Wq; c.s[2] = Wk; c.s[3] = Wv;
  c.d[0] = Xbf; c.d[1] = Wqb; c.d[2] = Wkb; c.d[3] = Wvb;
  cvt_all<<<7168, 256, 0, stream>>>(c);

  QkvArgs a;
  a.X = Xbf;
  a.W0 = Wqb; a.W1 = Wkb; a.W2 = Wvb;
  a.b0 = bq;  a.b1 = bk;  a.b2 = bv;
  a.o0 = qbuf; a.o1 = kbuf;
  a.vt = vTb;
  qkv_gemm<<<dim3(32, 8, 3), 256, 0, stream>>>(a);

  attn_kernel<<<dim3(16, 32), 256, 0, stream>>>(qbuf, kbuf, vTb, zbuf);

  ln_kernel<<<4096, 256, 0, stream>>>(emb, zbuf, gamma, beta, out);
}

// Round 10
// 182.283 us; speedup vs baseline: 1.0451x; 1.0451x over previous
//
#include <hip/hip_runtime.h>
#include <hip/hip_bf16.h>
#include <math.h>

// Problem constants: B=2, S=2048, D=1024, H=16, HD=64
typedef unsigned short ushort_t;
typedef unsigned char uchar_t;
typedef __attribute__((ext_vector_type(8))) short short8;   // 8 bf16 = 4 VGPRs (MFMA A/B frag)
typedef __attribute__((ext_vector_type(4))) float f32x4;    // MFMA C/D frag

struct __align__(8) us4 { ushort_t u[4]; };

__device__ __forceinline__ ushort_t f2bf(float x) {
  union { float f; unsigned u; } c; c.f = x;
  unsigned r = c.u + 0x7FFFu + ((c.u >> 16) & 1u);  // RNE
  return (ushort_t)(r >> 16);
}
__device__ __forceinline__ float bf2f(ushort_t b) {
  union { unsigned u; float f; } c; c.u = ((unsigned)b) << 16;
  return c.f;
}

// (1/sqrt(2048)) * log2(e): folded into Q at projection time so the QK^T
// MFMA emits log2-domain scores directly.
#define CEXP_SCALE (0.02209708691f * 1.44269504089f)

// ---------------------------------------------------------------------------
// fp32 -> bf16 bulk convert — all four arrays in one launch (verified r3).
// ---------------------------------------------------------------------------
struct CvtArgs { const float* s[4]; ushort_t* d[4]; };

__global__ __launch_bounds__(256) void cvt_all(CvtArgs c) {
  int bid = blockIdx.x;
  int job, base;
  if (bid < 4096) { job = 0; base = bid; }
  else { job = 1 + ((bid - 4096) >> 10); base = (bid - 4096) & 1023; }
  int i = (base * 256 + threadIdx.x) * 4;
  f32x4 v = *(const f32x4*)(c.s[job] + i);
  us4 o;
  o.u[0] = f2bf(v[0]); o.u[1] = f2bf(v[1]); o.u[2] = f2bf(v[2]); o.u[3] = f2bf(v[3]);
  *(us4*)(c.d[job] + i) = o;
}

// ---------------------------------------------------------------------------
// QKV projection GEMM — BK=64, NOW WITH CONFLICT-FREE LDS (r9 profile:
// 9.4M bank conflicts, 16-way on fragment reads at 128B row stride).
// Fix per rule #21 (linear dest + pre-swizzled SOURCE + XOR READ — the
// exact attn-Ks pattern, green since r0):
//   stage: lane reads global unit (lane&7)^(lane>>3) of its row -> LDS row r
//          slot su holds global unit su^(r&7)
//   read:  fragment unit u = kk*4+quad lives at slot (u^l7)
// -> 16 lanes hit 8 distinct 16B slots = 2-way aliasing (free, m136).
// Epilogues verbatim: z==0 Q scaled by CEXP_SCALE, z==1 K hd-swizzled,
// z==2 fp8 V^T key-swizzled.
// ---------------------------------------------------------------------------
struct QkvArgs {
  const ushort_t* X;
  const ushort_t* W0; const ushort_t* W1; const ushort_t* W2;
  const float* b0; const float* b1; const float* b2;
  ushort_t* o0; ushort_t* o1;
  uchar_t* vt;
};

__global__ __launch_bounds__(256) void qkv_gemm(QkvArgs a) {
  __shared__ __align__(16) ushort_t As[128 * 64];
  __shared__ __align__(16) ushort_t Bs[128 * 64];
  const int z = blockIdx.z;
  const ushort_t* W  = (z == 0) ? a.W0 : ((z == 1) ? a.W1 : a.W2);
  const float* bias  = (z == 0) ? a.b0 : ((z == 1) ? a.b1 : a.b2);
  const int mBase = blockIdx.x * 128;
  const int nBase = blockIdx.y * 128;
  const int tid  = threadIdx.x;
  const int lane = tid & 63;
  const int w    = tid >> 6;
  const int wm   = w >> 1, wn = w & 1;
  const int quad = lane >> 4;
  const int l15  = lane & 15;
  const int l7   = l15 & 7;

  f32x4 acc[4][4] = {};

  // Staging: chunk j covers rows j*8..j*8+7 (full 64-col width).
  // Per-lane row-in-chunk = lane>>3; SOURCE col unit swizzled by row:
  // (lane&7)^(lane>>3), so LDS row r slot su = global unit su^(r&7).
  const int srow = lane >> 3;
  const int scol = ((lane & 7) ^ srow) * 8;
  const ushort_t* gA0 = a.X + (mBase + srow) * 1024 + scol;
  const ushort_t* gB0 = W   + (nBase + srow) * 1024 + scol;

  for (int k0 = 0; k0 < 1024; k0 += 64) {
#pragma unroll
    for (int p = 0; p < 4; ++p) {
      int j = w * 4 + p;                      // 0..15
      __builtin_amdgcn_global_load_lds(
          (const __attribute__((address_space(1))) void*)(gA0 + j * 8 * 1024 + k0),
          (__attribute__((address_space(3))) void*)(As + j * 512), 16, 0, 0);
      __builtin_amdgcn_global_load_lds(
          (const __attribute__((address_space(1))) void*)(gB0 + j * 8 * 1024 + k0),
          (__attribute__((address_space(3))) void*)(Bs + j * 512), 16, 0, 0);
    }
    __syncthreads();
    short8 af[2][4], bfr[2][4];
#pragma unroll
    for (int kk = 0; kk < 2; ++kk) {
#pragma unroll
      for (int mi = 0; mi < 4; ++mi)
        af[kk][mi] = *(const short8*)(As + (wm * 64 + mi * 16 + l15) * 64 + (((kk * 4 + quad) ^ l7) * 8));
#pragma unroll
      for (int ni = 0; ni < 4; ++ni)
        bfr[kk][ni] = *(const short8*)(Bs + (wn * 64 + ni * 16 + l15) * 64 + (((kk * 4 + quad) ^ l7) * 8));
    }
#pragma unroll
    for (int kk = 0; kk < 2; ++kk)
#pragma unroll
      for (int mi = 0; mi < 4; ++mi)
#pragma unroll
        for (int ni = 0; ni < 4; ++ni)
          acc[mi][ni] = __builtin_amdgcn_mfma_f32_16x16x32_bf16(af[kk][mi], bfr[kk][ni], acc[mi][ni], 0, 0, 0);
    __syncthreads();
  }

  if (z == 2) {
    // ---- fused V epilogue: fp8 e4m3 V^T with key-unit XOR swizzle ----
#pragma unroll
    for (int ni = 0; ni < 4; ++ni) {
      int n = nBase + wn * 64 + ni * 16 + l15;
      float bv = bias[n];
      int h = n >> 6, hd = n & 63;
#pragma unroll
      for (int mi = 0; mi < 4; ++mi) {
        int m0 = mBase + wm * 64 + mi * 16 + quad * 4;
        int bb = m0 >> 11, s = m0 & 2047;
        float x0 = acc[mi][ni][0] + bv, x1 = acc[mi][ni][1] + bv;
        float x2 = acc[mi][ni][2] + bv, x3 = acc[mi][ni][3] + bv;
        unsigned int pk = __builtin_amdgcn_cvt_pk_fp8_f32(x0, x1, 0, false);
        pk = __builtin_amdgcn_cvt_pk_fp8_f32(x2, x3, pk, true);
        int dest = (s & ~127) + ((((s >> 4) & 7) ^ (hd & 7)) * 16) + (s & 15);
        *(unsigned int*)(a.vt + (size_t)(bb * 16 + h) * 131072 + (size_t)hd * 2048 + dest) = pk;
      }
    }
  } else {
    ushort_t* out = (z == 0) ? a.o0 : a.o1;
    const int swz = (z == 1) ? 7 : 0;            // hd-unit swizzle mask (K only)
    const float osc = (z == 0) ? CEXP_SCALE : 1.0f;  // fold softmax scale into Q
#pragma unroll
    for (int ni = 0; ni < 4; ++ni) {
      int n = nBase + wn * 64 + ni * 16 + l15;
      float bv = bias[n];
      int h = n >> 6, hd = n & 63;
      int hdHi = hd >> 3, hdLo = hd & 7;
#pragma unroll
      for (int mi = 0; mi < 4; ++mi) {
        int m0 = mBase + wm * 64 + mi * 16 + quad * 4;
#pragma unroll
        for (int r = 0; r < 4; ++r) {
          int m = m0 + r;
          int bb = m >> 11, s = m & 2047;
          int hdw = (((hdHi ^ (s & swz)) << 3) | hdLo);
          out[((bb * 16 + h) * 2048 + s) * 64 + hdw] = f2bf((acc[mi][ni][r] + bv) * osc);
        }
      }
    }
  }
}

// ---------------------------------------------------------------------------
// Attention — EXACT r5 GREEN TEXT (51.6 us verified). Two-barrier KT=128
// schedule, 4 waves x 32 q-rows, r5 remap, needP/boundary block-uniform,
// CEXP folded upstream. FROZEN after 3 NaN strikes on geometry restructures.
// ---------------------------------------------------------------------------
__global__ __launch_bounds__(256) void attn_kernel(const ushort_t* __restrict__ qb,
                                                   const ushort_t* __restrict__ kb,
                                                   const uchar_t* __restrict__ vT,
                                                   ushort_t* __restrict__ zb) {
  __shared__ __align__(16) ushort_t Ks[128 * 64];   // [key][hd] swizzled bf16
  __shared__ __align__(16) uchar_t  Vt[64 * 128];   // [hd][key] swizzled fp8
  __shared__ __align__(16) uchar_t  Ps[128 * 128];  // [q][key] swizzled fp8 (wave-private rows)
  // ---- bijective block remap (512 = 8 xcd * 2 hi * 8 xb * 4 ylo) ----
  const int n_lin = blockIdx.x + 16 * blockIdx.y;
  const int xcd = n_lin & 7;
  const int j   = n_lin >> 3;           // 0..63
  const int hi  = (j >> 5) & 1;
  const int xb  = (j >> 2) & 7;
  const int xq  = hi ? (15 - xb) : xb;  // 0..15
  const int bh  = xcd * 4 + (j & 3);    // 0..31

  const int qblk = xq * 128;
  const int tid  = threadIdx.x;
  const int lane = tid & 63;
  const int w    = tid >> 6;
  const int quad = lane >> 4;
  const int l15  = lane & 15;
  const int l7   = l15 & 7;

  const ushort_t* qpage = qb + (size_t)bh * (2048 * 64);
  const ushort_t* kpage = kb + (size_t)bh * (2048 * 64);
  const uchar_t*  vpage = vT + (size_t)bh * (64 * 2048);

  // Q fragments (constant across key tiles; Q global layout is linear)
  short8 qf[2][2];
#pragma unroll
  for (int nb = 0; nb < 2; ++nb) {
    int qg = qblk + w * 32 + nb * 16 + l15;
#pragma unroll
    for (int kd = 0; kd < 2; ++kd)
      qf[nb][kd] = *(const short8*)(qpage + (size_t)qg * 64 + kd * 32 + quad * 8);
  }

  float psum[2] = {0.f, 0.f};
  f32x4 o[4][2] = {};  // O^T: [hd block][q block]

  for (int kt = 0; kt < 2048; kt += 128) {
    const bool needP    = (kt >= qblk);   // block-uniform: PV work in this tile
    const bool boundary = (kt == qblk);   // block-uniform: only tile needing mask
    __syncthreads();  // prior tile's LDS reads complete before DMA overwrite

    // ---- async stage K tile (16 KB, 4 chunks/wave) ----
#pragma unroll
    for (int p = 0; p < 4; ++p) {
      int jj = w * 4 + p;
      __builtin_amdgcn_global_load_lds(
          (const __attribute__((address_space(1))) void*)(kpage + (size_t)kt * 64 + jj * 512 + lane * 8),
          (__attribute__((address_space(3))) void*)(Ks + jj * 512), 16, 0, 0);
    }
    // ---- async stage V^T tile (8 KB fp8, 2 chunks/wave) ----
    if (needP) {
#pragma unroll
      for (int p = 0; p < 2; ++p) {
        int jj = w * 2 + p;
        __builtin_amdgcn_global_load_lds(
            (const __attribute__((address_space(1))) void*)(vpage + (size_t)(jj * 8 + (lane >> 3)) * 2048 + kt + (lane & 7) * 16),
            (__attribute__((address_space(3))) void*)(Vt + jj * 1024), 16, 0, 0);
      }
    }
    __syncthreads();  // drain vmcnt -> staged data visible

    // ---- S^T = K*Q^T per 16-key slice; exp + psum + fp8 P pack ----
#pragma unroll
    for (int mb = 0; mb < 8; ++mb) {
      const ushort_t* krow = Ks + (mb * 16 + l15) * 64;
      short8 kf0 = *(const short8*)(krow + ((0 + quad) ^ l7) * 8);
      short8 kf1 = *(const short8*)(krow + ((4 + quad) ^ l7) * 8);
      f32x4 s0 = {}, s1 = {};
      s0 = __builtin_amdgcn_mfma_f32_16x16x32_bf16(kf0, qf[0][0], s0, 0, 0, 0);
      s0 = __builtin_amdgcn_mfma_f32_16x16x32_bf16(kf1, qf[0][1], s0, 0, 0, 0);
      s1 = __builtin_amdgcn_mfma_f32_16x16x32_bf16(kf0, qf[1][0], s1, 0, 0, 0);
      s1 = __builtin_amdgcn_mfma_f32_16x16x32_bf16(kf1, qf[1][1], s1, 0, 0, 0);
      const int keyb = kt + mb * 16 + quad * 4;
#pragma unroll
      for (int nb = 0; nb < 2; ++nb) {
        f32x4 s = nb ? s1 : s0;
        float p0 = __builtin_amdgcn_exp2f(s[0]);
        float p1 = __builtin_amdgcn_exp2f(s[1]);
        float p2 = __builtin_amdgcn_exp2f(s[2]);
        float p3 = __builtin_amdgcn_exp2f(s[3]);
        psum[nb] += (p0 + p1) + (p2 + p3);  // denominator: ALL keys (mask is post-softmax)
        if (needP) {
          unsigned int pk;
          if (boundary) {
            int qg = qblk + w * 32 + nb * 16 + l15;
            float m0 = (keyb + 0 >= qg) ? p0 : 0.f;
            float m1 = (keyb + 1 >= qg) ? p1 : 0.f;
            float m2 = (keyb + 2 >= qg) ? p2 : 0.f;
            float m3 = (keyb + 3 >= qg) ? p3 : 0.f;
            pk = __builtin_amdgcn_cvt_pk_fp8_f32(m0, m1, 0, false);
            pk = __builtin_amdgcn_cvt_pk_fp8_f32(m2, m3, pk, true);
          } else {
            pk = __builtin_amdgcn_cvt_pk_fp8_f32(p0, p1, 0, false);
            pk = __builtin_amdgcn_cvt_pk_fp8_f32(p2, p3, pk, true);
          }
          *(unsigned int*)(Ps + (w * 32 + nb * 16 + l15) * 128 + ((mb ^ l7) * 16) + quad * 4) = pk;
        }
      }
    }

    // ---- O^T += V^T * P^T in fp8 (skip fully-masked tiles) ----
    if (needP) {
#pragma unroll
      for (int kd = 0; kd < 4; ++kd) {
        const int un = ((kd * 2 + (quad >> 1)) ^ l7) * 16 + (quad & 1) * 8;
        long long pf0 = *(const long long*)(Ps + (w * 32 + l15) * 128 + un);
        long long pf1 = *(const long long*)(Ps + (w * 32 + 16 + l15) * 128 + un);
#pragma unroll
        for (int mb = 0; mb < 4; ++mb) {
          long long vf = *(const long long*)(Vt + (mb * 16 + l15) * 128 + un);
          o[mb][0] = __builtin_amdgcn_mfma_f32_16x16x32_fp8_fp8(vf, pf0, o[mb][0], 0, 0, 0);
          o[mb][1] = __builtin_amdgcn_mfma_f32_16x16x32_fp8_fp8(vf, pf1, o[mb][1], 0, 0, 0);
        }
      }
    }
  }

  // ---- final denominator reduce (across quads) + store ----
#pragma unroll
  for (int nb = 0; nb < 2; ++nb) {
    psum[nb] += __shfl_xor(psum[nb], 16, 64);
    psum[nb] += __shfl_xor(psum[nb], 32, 64);
    float rl = 1.0f / psum[nb];
    int qg = qblk + w * 32 + nb * 16 + l15;
#pragma unroll
    for (int mb = 0; mb < 4; ++mb)
#pragma unroll
      for (int r = 0; r < 4; ++r) {
        int hd = mb * 16 + quad * 4 + r;
        zb[((size_t)bh * 2048 + qg) * 64 + hd] = f2bf(o[mb][nb][r] * rl);
      }
  }
}

// ---------------------------------------------------------------------------
// Residual + LayerNorm with the reference's scrambled .view(b,s,-1) remap
// ---------------------------------------------------------------------------
__global__ __launch_bounds__(256) void ln_kernel(const float* __restrict__ emb,
                                                 const ushort_t* __restrict__ zb,
                                                 const float* __restrict__ gamma,
                                                 const float* __restrict__ beta,
                                                 float* __restrict__ out) {
  __shared__ float red[2][4];
  int row = blockIdx.x;
  int b = row >> 11, s = row & 2047;
  int h = s >> 7;
  int siHi = (s & 127) << 4;
  int tid = threadIdx.x;
  int dcol = tid * 4;
  int si = siHi | (dcol >> 6);
  int j = dcol & 63;

  f32x4 e4 = *(const f32x4*)(emb + (size_t)row * 1024 + dcol);
  us4 z4 = *(const us4*)(zb + (((size_t)(b * 16 + h) * 2048 + si) * 64 + j));
  float x0 = e4[0] + bf2f(z4.u[0]);
  float x1 = e4[1] + bf2f(z4.u[1]);
  float x2 = e4[2] + bf2f(z4.u[2]);
  float x3 = e4[3] + bf2f(z4.u[3]);

  float sum = x0 + x1 + x2 + x3;
  float sq  = x0 * x0 + x1 * x1 + x2 * x2 + x3 * x3;
#pragma unroll
  for (int off = 1; off <= 32; off <<= 1) {
    sum += __shfl_xor(sum, off, 64);
    sq  += __shfl_xor(sq,  off, 64);
  }
  int wv = tid >> 6;
  if ((tid & 63) == 0) { red[0][wv] = sum; red[1][wv] = sq; }
  __syncthreads();
  float ts = red[0][0] + red[0][1] + red[0][2] + red[0][3];
  float tq = red[1][0] + red[1][1] + red[1][2] + red[1][3];
  float mu = ts * (1.0f / 1024.0f);
  float var = tq * (1.0f / 1024.0f) - mu * mu;
  float rsig = rsqrtf(var + 1e-5f);

  f32x4 g4 = *(const f32x4*)(gamma + dcol);
  f32x4 b4 = *(const f32x4*)(beta + dcol);
  f32x4 o4;
  o4[0] = (x0 - mu) * rsig * g4[0] + b4[0];
  o4[1] = (x1 - mu) * rsig * g4[1] + b4[1];
  o4[2] = (x2 - mu) * rsig * g4[2] + b4[2];
  o4[3] = (x3 - mu) * rsig * g4[3] + b4[3];
  *(f32x4*)(out + (size_t)row * 1024 + dcol) = o4;
}

// ---------------------------------------------------------------------------
extern "C" void kernel_launch(void* const* d_in, const int* in_sizes, int n_in,
                              void* d_out, int out_size, void* d_ws, size_t ws_size,
                              hipStream_t stream) {
  (void)in_sizes; (void)n_in; (void)out_size; (void)ws_size;
  const float* emb   = (const float*)d_in[0];
  const float* Wq    = (const float*)d_in[1];
  const float* bq    = (const float*)d_in[2];
  const float* Wk    = (const float*)d_in[3];
  const float* bk    = (const float*)d_in[4];
  const float* Wv    = (const float*)d_in[5];
  const float* bv    = (const float*)d_in[6];
  const float* gamma = (const float*)d_in[7];
  const float* beta  = (const float*)d_in[8];
  float* out = (float*)d_out;

  char* ws = (char*)d_ws;
  ushort_t* Xbf  = (ushort_t*)(ws);                    // 8,388,608 B
  ushort_t* Wqb  = (ushort_t*)(ws + 8388608);          // 2,097,152 B each
  ushort_t* Wkb  = (ushort_t*)(ws + 10485760);
  ushort_t* Wvb  = (ushort_t*)(ws + 12582912);
  ushort_t* qbuf = (ushort_t*)(ws + 14680064);         // 8,388,608 B (pre-scaled by CEXP)
  ushort_t* kbuf = (ushort_t*)(ws + 23068672);         // 8,388,608 B (hd-swizzled)
  ushort_t* zbuf = (ushort_t*)(ws + 31457280);         // attn output
  uchar_t*  vTb  = (uchar_t*)(ws + 39845888);          // 4,194,304 B fp8 V^T (key-swizzled)

  CvtArgs c;
  c.s[0] = emb; c.s[1] = Wq; c.s[2] = Wk; c.s[3] = Wv;
  c.d[0] = Xbf; c.d[1] = Wqb; c.d[2] = Wkb; c.d[3] = Wvb;
  cvt_all<<<7168, 256, 0, stream>>>(c);

  QkvArgs a;
  a.X = Xbf;
  a.W0 = Wqb; a.W1 = Wkb; a.W2 = Wvb;
  a.b0 = bq;  a.b1 = bk;  a.b2 = bv;
  a.o0 = qbuf; a.o1 = kbuf;
  a.vt = vTb;
  qkv_gemm<<<dim3(32, 8, 3), 256, 0, stream>>>(a);

  attn_kernel<<<dim3(16, 32), 256, 0, stream>>>(qbuf, kbuf, vTb, zbuf);

  ln_kernel<<<4096, 256, 0, stream>>>(emb, zbuf, gamma, beta, out);
}